// Round 9
// baseline (895.405 us; speedup 1.0000x reference)
//
#include <hip/hip_runtime.h>
#include <hip/hip_bf16.h>

#define NN 50000
#define EE 800000
#define HD 64
#define LL 14
#define IND 128
#define OUTD 112
#define LN2 0.69314718056f
#define LUTN 1537   // code 0 = padding (0,0); codes 1..1536 <-> bf16 bits 16256..17791

typedef __attribute__((ext_vector_type(8))) short short8;
typedef __attribute__((ext_vector_type(2))) float float2_;
typedef __attribute__((ext_vector_type(4))) float float4_;
typedef __attribute__((ext_vector_type(4))) unsigned short ushort4_;

__device__ __forceinline__ short bf16_hi(float x) {
    return (short)(__float_as_uint(x) >> 16);  // truncation split
}
__device__ __forceinline__ float bf16_f(short s) {
    return __uint_as_float(((unsigned)(unsigned short)s) << 16);
}
// round-to-nearest-even fp32 -> bf16 bits
__device__ __forceinline__ unsigned short f2b_rne(float x) {
    unsigned u = __float_as_uint(x);
    u += 0x7fffu + ((u >> 16) & 1u);
    return (unsigned short)(u >> 16);
}
// msg -> 16-bit code (p = exp(msg) >= 1 always)
__device__ __forceinline__ unsigned short msg2code(float msg) {
    int c = (int)f2b_rne(__expf(msg)) - 16255;
    return (unsigned short)min(c, 1536);
}

// split 8 consecutive fp32 (16B-aligned) into bf16 hi/lo fragments
__device__ __forceinline__ void split8(const float* p, short8& hi, short8& lo) {
    float4_ a = *(const float4_*)p;
    float4_ b = *(const float4_*)(p + 4);
    float v[8] = {a[0], a[1], a[2], a[3], b[0], b[1], b[2], b[3]};
    #pragma unroll
    for (int j = 0; j < 8; ++j) {
        short h = bf16_hi(v[j]);
        hi[j] = h;
        lo[j] = bf16_hi(v[j] - bf16_f(h));
    }
}

// load B-fragment (8 k-rows of one 16-col slice) from global weights, hi/lo split
__device__ __forceinline__ void load_b(const float* __restrict__ W, int ldw,
                                       int colbase, int krow, short8& hi, short8& lo) {
    #pragma unroll
    for (int j = 0; j < 8; ++j) {
        float wv = W[(krow + j) * ldw + colbase];
        short h = bf16_hi(wv);
        hi[j] = h;
        lo[j] = bf16_hi(wv - bf16_f(h));
    }
}

// fp32-accurate product via 3 bf16 MFMAs (drop lo*lo)
__device__ __forceinline__ float4_ mm3(short8 ah, short8 al, short8 bh, short8 bl,
                                       float4_ acc) {
    acc = __builtin_amdgcn_mfma_f32_16x16x32_bf16(ah, bh, acc, 0, 0, 0);
    acc = __builtin_amdgcn_mfma_f32_16x16x32_bf16(al, bh, acc, 0, 0, 0);
    acc = __builtin_amdgcn_mfma_f32_16x16x32_bf16(ah, bl, acc, 0, 0, 0);
    return acc;
}

// ---------------- CSR build ----------------

__global__ void k_hist(const int* __restrict__ ei, int* __restrict__ cnt,
                       int* __restrict__ rank) {
    int e = blockIdx.x * blockDim.x + threadIdx.x;
    if (e < EE) rank[e] = atomicAdd(&cnt[ei[EE + e]], 1);
}

__global__ __launch_bounds__(1024) void k_scan1(const int* __restrict__ deg,
                                                int* __restrict__ excl,
                                                int* __restrict__ bsum) {
    __shared__ int ws[16];
    int tid = threadIdx.x, lane = tid & 63, w = tid >> 6;
    int gid = blockIdx.x * 1024 + tid;
    int v = (gid < NN) ? deg[gid] : 0;
    int x = v;
    #pragma unroll
    for (int d = 1; d < 64; d <<= 1) {
        int y = __shfl_up(x, d);
        if (lane >= d) x += y;
    }
    if (lane == 63) ws[w] = x;
    __syncthreads();
    if (tid == 0) {
        int acc = 0;
        for (int i = 0; i < 16; i++) { int t = ws[i]; ws[i] = acc; acc += t; }
        bsum[blockIdx.x] = acc;
    }
    __syncthreads();
    if (gid < NN) excl[gid] = x - v + ws[w];
}

__global__ void k_scan2(const int* __restrict__ bsum, int* __restrict__ boff, int nb) {
    if (threadIdx.x == 0) {
        int acc = 0;
        for (int i = 0; i < nb; i++) { boff[i] = acc; acc += bsum[i]; }
    }
}

__global__ __launch_bounds__(1024) void k_scan3(int* __restrict__ rp,
                                                const int* __restrict__ boff) {
    int gid = blockIdx.x * 1024 + threadIdx.x;
    if (gid < NN) rp[gid] += boff[blockIdx.x];
    if (gid == 0) rp[NN] = EE;
}

__global__ void k_scatter(const int* __restrict__ ei, const int* __restrict__ rp,
                          const int* __restrict__ rank, int* __restrict__ csrc) {
    int e = blockIdx.x * blockDim.x + threadIdx.x;
    if (e < EE) {
        int d = ei[EE + e];
        csrc[rp[d] + rank[e]] = ei[e];
    }
}

// ---------------- Encoder: h0 = x @ enc_W + enc_b, plus code0 ----------------

__global__ __launch_bounds__(256) void k_enc(const float* __restrict__ x,
                                             const float* __restrict__ W,
                                             const float* __restrict__ b,
                                             float* __restrict__ h,
                                             unsigned short* __restrict__ C0) {
    __shared__ float X[16 * 132];
    int tid = threadIdx.x, lane = tid & 63, w = tid >> 6;
    int nb = blockIdx.x * 16;
    int nq = lane >> 4, nr = lane & 15;
    int colbase = w * 16 + nr;

    {
        const float* src = x + (size_t)nb * IND + tid * 8;
        float4_ a = *(const float4_*)src;
        float4_ c = *(const float4_*)(src + 4);
        int m = tid >> 4, k8 = 8 * (tid & 15);
        *(float4_*)&X[m * 132 + k8] = a;
        *(float4_*)&X[m * 132 + k8 + 4] = c;
    }
    __syncthreads();

    float4_ acc = {};
    #pragma unroll
    for (int t = 0; t < 4; ++t) {
        short8 ah, al, bh, bl;
        split8(&X[nr * 132 + t * 32 + nq * 8], ah, al);
        load_b(W, HD, colbase, t * 32 + nq * 8, bh, bl);
        acc = mm3(ah, al, bh, bl, acc);
    }

    float bias = b[colbase];
    #pragma unroll
    for (int r = 0; r < 4; ++r) {
        int node = nb + nq * 4 + r;
        float y = acc[r] + bias;
        h[node * HD + colbase] = y;
        float msg = fminf(fmaxf(y, 0.f) + 1e-7f, 50.f);
        C0[node * HD + colbase] = msg2code(msg);
    }
}

// ---------------- GENConv layer: LUT-gather softmax agg (merged 4-node,
//                  quarter-wave) + MFMA matmul + residual + fused prenorm ----------------

__global__ __launch_bounds__(256) void k_layer(const unsigned short* __restrict__ Cin,
                                               const float* __restrict__ selfh,  // layer0 only
                                               const float* __restrict__ hres,
                                               float* __restrict__ hout,
                                               unsigned short* __restrict__ Cout,
                                               const int* __restrict__ rp,
                                               const int* __restrict__ csrc,
                                               const float* __restrict__ W,
                                               const float* __restrict__ b,
                                               const float* __restrict__ gnext,
                                               const float* __restrict__ bnext) {
    __shared__ float T[16 * 68];          // 4.25 KB
    __shared__ float L2lut[2 * 1540];     // 12.3 KB: (p, p*ln p) per code
    int tid = threadIdx.x, lane = tid & 63, w = tid >> 6;
    int nb = blockIdx.x * 16;
    int nq = lane >> 4, nr = lane & 15;
    int colbase = w * 16 + nr;

    // build LUT (exact for bf16-quantized p)
    for (int c = tid; c < LUTN; c += 256) {
        float p = 0.f, q = 0.f;
        if (c > 0) {
            p = __uint_as_float((unsigned)(16255 + c) << 16);
            q = p * (LN2 * __log2f(p));
        }
        L2lut[2 * c] = p;
        L2lut[2 * c + 1] = q;
    }

    // B fragments, register-resident
    short8 Bhi[2], Blo[2];
    #pragma unroll
    for (int t = 0; t < 2; ++t)
        load_b(W, HD, colbase, t * 32 + nq * 8, Bhi[t], Blo[t]);
    __syncthreads();  // LUT ready

    // merged gather over the wave's 4 nodes; quarter-wave edge batching:
    // group g (lane>>4) owns edge k*4+g; lane covers channels ci*4..ci*4+3.
    int g = lane >> 4;
    int ci = lane & 15;
    int node0 = nb + w * 4;
    int r0 = rp[node0], r1 = rp[node0 + 1], r2 = rp[node0 + 2],
        r3 = rp[node0 + 3], r4 = rp[node0 + 4];
    int beg[4] = {r0, r1, r2, r3};
    int deg[4] = {r1 - r0, r2 - r1, r3 - r2, r4 - r3};
    int maxdeg = max(max(deg[0], deg[1]), max(deg[2], deg[3]));

    float S[4][4] = {{0.f}}, Nq[4][4] = {{0.f}};
    for (int chunk = 0; chunk < maxdeg; chunk += 64) {
        int myidx[4];
        #pragma unroll
        for (int i = 0; i < 4; ++i) {
            myidx[i] = -1;
            if (chunk + lane < deg[i]) myidx[i] = csrc[beg[i] + chunk + lane];
        }
        int cmax = min(64, maxdeg - chunk);
        int nb4 = (cmax + 3) >> 2;
        for (int k = 0; k < nb4; ++k) {
            unsigned d0[4], d1[4];
            #pragma unroll
            for (int i = 0; i < 4; ++i) {
                int src = __shfl(myidx[i], k * 4 + g);
                const unsigned* pp =
                    (const unsigned*)(Cin + ((size_t)max(src, 0) << 6)) + ci * 2;
                unsigned a0 = pp[0], a1 = pp[1];
                bool act = src >= 0;
                d0[i] = act ? a0 : 0u;   // code 0 -> (0,0): pad contributes nothing
                d1[i] = act ? a1 : 0u;
            }
            #pragma unroll
            for (int i = 0; i < 4; ++i) {
                unsigned c0 = d0[i] & 0xffffu, c1 = d0[i] >> 16;
                unsigned c2 = d1[i] & 0xffffu, c3 = d1[i] >> 16;
                float2_ pq0 = *(const float2_*)&L2lut[c0 * 2];
                float2_ pq1 = *(const float2_*)&L2lut[c1 * 2];
                float2_ pq2 = *(const float2_*)&L2lut[c2 * 2];
                float2_ pq3 = *(const float2_*)&L2lut[c3 * 2];
                S[i][0] += pq0[0]; Nq[i][0] += pq0[1];
                S[i][1] += pq1[0]; Nq[i][1] += pq1[1];
                S[i][2] += pq2[0]; Nq[i][2] += pq2[1];
                S[i][3] += pq3[0]; Nq[i][3] += pq3[1];
            }
        }
    }

    // reduce across the 4 quarter-wave groups, finalize agg, write T
    #pragma unroll
    for (int i = 0; i < 4; ++i) {
        float s0 = S[i][0], s1 = S[i][1], s2 = S[i][2], s3 = S[i][3];
        float n0 = Nq[i][0], n1 = Nq[i][1], n2 = Nq[i][2], n3 = Nq[i][3];
        #pragma unroll
        for (int d = 16; d < 64; d <<= 1) {
            s0 += __shfl_xor(s0, d); s1 += __shfl_xor(s1, d);
            s2 += __shfl_xor(s2, d); s3 += __shfl_xor(s3, d);
            n0 += __shfl_xor(n0, d); n1 += __shfl_xor(n1, d);
            n2 += __shfl_xor(n2, d); n3 += __shfl_xor(n3, d);
        }
        if (g == 0) {
            int node = node0 + i;
            float a0 = n0 / fmaxf(s0, 1e-16f);
            float a1 = n1 / fmaxf(s1, 1e-16f);
            float a2 = n2 / fmaxf(s2, 1e-16f);
            float a3 = n3 / fmaxf(s3, 1e-16f);
            float4_ xv;
            if (selfh) {
                float4_ sf = *(const float4_*)&selfh[(size_t)node * HD + ci * 4];
                xv[0] = sf[0] + a0; xv[1] = sf[1] + a1;
                xv[2] = sf[2] + a2; xv[3] = sf[3] + a3;
            } else {
                const unsigned* pp = (const unsigned*)(Cin + ((size_t)node << 6)) + ci * 2;
                unsigned e0 = pp[0], e1 = pp[1];
                float2_ q0 = *(const float2_*)&L2lut[(e0 & 0xffffu) * 2];
                float2_ q1 = *(const float2_*)&L2lut[(e0 >> 16) * 2];
                float2_ q2 = *(const float2_*)&L2lut[(e1 & 0xffffu) * 2];
                float2_ q3 = *(const float2_*)&L2lut[(e1 >> 16) * 2];
                // msg = q/p = ln(p); y = msg - eps
                xv[0] = __fdividef(q0[1], q0[0]) - 1e-7f + a0;
                xv[1] = __fdividef(q1[1], q1[0]) - 1e-7f + a1;
                xv[2] = __fdividef(q2[1], q2[0]) - 1e-7f + a2;
                xv[3] = __fdividef(q3[1], q3[0]) - 1e-7f + a3;
            }
            *(float4_*)&T[(w * 4 + i) * 68 + ci * 4] = xv;
        }
    }
    __syncthreads();

    short8 Ahi[2], Alo[2];
    #pragma unroll
    for (int t = 0; t < 2; ++t)
        split8(&T[nr * 68 + t * 32 + nq * 8], Ahi[t], Alo[t]);
    __syncthreads();  // all A reads done before T is overwritten

    float4_ acc = {};
    #pragma unroll
    for (int t = 0; t < 2; ++t)
        acc = mm3(Ahi[t], Alo[t], Bhi[t], Blo[t], acc);

    float bias = b[colbase];
    #pragma unroll
    for (int r = 0; r < 4; ++r) {
        int m = nq * 4 + r;
        int node = nb + m;
        float v = acc[r] + bias;
        if (hres) v += hres[node * HD + colbase];
        hout[node * HD + colbase] = v;
        T[m * 68 + colbase] = v;
    }
    if (!Cout) return;
    __syncthreads();

    // LN phase: thread -> node tid>>4, 4 channels; emit codes
    int m = tid >> 4, c4 = (tid & 15) * 4;
    float4_ vv = *(const float4_*)&T[m * 68 + c4];
    float ps_ = (vv[0] + vv[1]) + (vv[2] + vv[3]);
    float pq_ = (vv[0] * vv[0] + vv[1] * vv[1]) + (vv[2] * vv[2] + vv[3] * vv[3]);
    #pragma unroll
    for (int d = 8; d; d >>= 1) {
        ps_ += __shfl_xor(ps_, d);
        pq_ += __shfl_xor(pq_, d);
    }
    float mu = ps_ * (1.f / 64.f);
    float var = pq_ * (1.f / 64.f) - mu * mu;
    float inv = rsqrtf(fmaxf(var, 0.f) + 1e-5f);
    float4_ g4 = *(const float4_*)&gnext[c4];
    float4_ b4 = *(const float4_*)&bnext[c4];
    ushort4_ po;
    #pragma unroll
    for (int j = 0; j < 4; ++j) {
        float y = fmaxf((vv[j] - mu) * inv * g4[j] + b4[j], 0.f);
        float msg = fminf(y + 1e-7f, 50.f);
        po[j] = msg2code(msg);
    }
    *(ushort4_*)&Cout[(nb + m) * HD + c4] = po;
}

// ---------------- Predictor: out = h @ pred_W + pred_b  (MFMA) ----------------

__global__ __launch_bounds__(256) void k_pred(const float* __restrict__ h,
                                              const float* __restrict__ W,
                                              const float* __restrict__ b,
                                              float* __restrict__ out) {
    __shared__ float T[16 * 68];
    int tid = threadIdx.x, lane = tid & 63, w = tid >> 6;
    int nb = blockIdx.x * 16;
    int nq = lane >> 4, nr = lane & 15;

    {
        const float* src = h + (size_t)nb * HD + tid * 4;
        float4_ a = *(const float4_*)src;
        int m = tid >> 4, k4 = 4 * (tid & 15);
        *(float4_*)&T[m * 68 + k4] = a;
    }
    __syncthreads();

    short8 Ahi[2], Alo[2];
    #pragma unroll
    for (int t = 0; t < 2; ++t)
        split8(&T[nr * 68 + t * 32 + nq * 8], Ahi[t], Alo[t]);

    for (int tt = w; tt < 7; tt += 4) {
        int colbase = tt * 16 + nr;
        float4_ acc = {};
        #pragma unroll
        for (int t = 0; t < 2; ++t) {
            short8 bh, bl;
            load_b(W, OUTD, colbase, t * 32 + nq * 8, bh, bl);
            acc = mm3(Ahi[t], Alo[t], bh, bl, acc);
        }
        float bias = b[colbase];
        #pragma unroll
        for (int r = 0; r < 4; ++r) {
            int node = nb + nq * 4 + r;
            out[node * OUTD + colbase] = acc[r] + bias;
        }
    }
}

// ---------------- Launch ----------------

extern "C" void kernel_launch(void* const* d_in, const int* in_sizes, int n_in,
                              void* d_out, int out_size, void* d_ws, size_t ws_size,
                              hipStream_t stream) {
    const float* x    = (const float*)d_in[0];
    const int*   ei   = (const int*)d_in[1];
    const float* encW = (const float*)d_in[2];
    const float* encb = (const float*)d_in[3];
    const float* lng  = (const float*)d_in[4];
    const float* lnb  = (const float*)d_in[5];
    const float* mlpW = (const float*)d_in[6];
    const float* mlpb = (const float*)d_in[7];
    const float* pW   = (const float*)d_in[8];
    const float* pb   = (const float*)d_in[9];
    float* out = (float*)d_out;

    float* hA  = (float*)d_ws;
    float* hB  = hA + (size_t)NN * HD;
    unsigned short* CA = (unsigned short*)(hB + (size_t)NN * HD);
    unsigned short* CB = CA + (size_t)NN * HD;
    int* rp   = (int*)(CB + (size_t)NN * HD);
    int* cnt  = rp + (NN + 1);
    int* csrc = cnt + NN;
    int* rank = csrc + EE;
    int* bsum = rank + EE;
    int* boff = bsum + 64;

    // CSR build (per call; ws is re-poisoned each launch)
    hipMemsetAsync(cnt, 0, NN * sizeof(int), stream);
    k_hist<<<(EE + 255) / 256, 256, 0, stream>>>(ei, cnt, rank);
    const int NB = (NN + 1023) / 1024;  // 49
    k_scan1<<<NB, 1024, 0, stream>>>(cnt, rp, bsum);
    k_scan2<<<1, 64, 0, stream>>>(bsum, boff, NB);
    k_scan3<<<NB, 1024, 0, stream>>>(rp, boff);
    k_scatter<<<(EE + 255) / 256, 256, 0, stream>>>(ei, rp, rank, csrc);

    // Encoder -> h_0 in hA, codes_0 in CA
    k_enc<<<NN / 16, 256, 0, stream>>>(x, encW, encb, hA, CA);

    // Layer 0: self term = raw h0; writes h_1 -> hB, codes_1 -> CB
    k_layer<<<NN / 16, 256, 0, stream>>>(CA, hA, nullptr, hB, CB, rp, csrc,
                                         mlpW, mlpb, lng, lnb);

    float* hres = hB;   // h_1
    float* hdst = hA;
    unsigned short* cc = CB;
    unsigned short* cn = CA;
    for (int l = 1; l < LL; ++l) {
        bool last = (l == LL - 1);
        k_layer<<<NN / 16, 256, 0, stream>>>(cc, nullptr, hres, hdst,
                                             last ? nullptr : cn,
                                             rp, csrc,
                                             mlpW + (size_t)l * HD * HD,
                                             mlpb + (size_t)l * HD,
                                             last ? nullptr : lng + (size_t)l * HD,
                                             last ? nullptr : lnb + (size_t)l * HD);
        float* t = hres; hres = hdst; hdst = t;
        unsigned short* u = cc; cc = cn; cn = u;
    }

    // Predictor on h_14
    k_pred<<<NN / 16, 256, 0, stream>>>(hres, pW, pb, out);
}

// Round 10
// 790.157 us; speedup vs baseline: 1.1332x; 1.1332x over previous
//
#include <hip/hip_runtime.h>
#include <hip/hip_bf16.h>

#define NN 50000
#define EE 800000
#define HD 64
#define LL 14
#define IND 128
#define OUTD 112
#define LN2 0.69314718056f

typedef __attribute__((ext_vector_type(8))) short short8;
typedef __attribute__((ext_vector_type(4))) float float4_;
typedef __attribute__((ext_vector_type(4))) unsigned short ushort4_;

__device__ __forceinline__ short bf16_hi(float x) {
    return (short)(__float_as_uint(x) >> 16);  // truncation split
}
__device__ __forceinline__ float bf16_f(short s) {
    return __uint_as_float(((unsigned)(unsigned short)s) << 16);
}
// round-to-nearest-even fp32 -> bf16 bits
__device__ __forceinline__ unsigned short f2b_rne(float x) {
    unsigned u = __float_as_uint(x);
    u += 0x7fffu + ((u >> 16) & 1u);
    return (unsigned short)(u >> 16);
}

// split 8 consecutive fp32 (16B-aligned) into bf16 hi/lo fragments
__device__ __forceinline__ void split8(const float* p, short8& hi, short8& lo) {
    float4_ a = *(const float4_*)p;
    float4_ b = *(const float4_*)(p + 4);
    float v[8] = {a[0], a[1], a[2], a[3], b[0], b[1], b[2], b[3]};
    #pragma unroll
    for (int j = 0; j < 8; ++j) {
        short h = bf16_hi(v[j]);
        hi[j] = h;
        lo[j] = bf16_hi(v[j] - bf16_f(h));
    }
}

// load B-fragment (8 k-rows of one 16-col slice) from global weights, hi/lo split
__device__ __forceinline__ void load_b(const float* __restrict__ W, int ldw,
                                       int colbase, int krow, short8& hi, short8& lo) {
    #pragma unroll
    for (int j = 0; j < 8; ++j) {
        float wv = W[(krow + j) * ldw + colbase];
        short h = bf16_hi(wv);
        hi[j] = h;
        lo[j] = bf16_hi(wv - bf16_f(h));
    }
}

// fp32-accurate product via 3 bf16 MFMAs (drop lo*lo)
__device__ __forceinline__ float4_ mm3(short8 ah, short8 al, short8 bh, short8 bl,
                                       float4_ acc) {
    acc = __builtin_amdgcn_mfma_f32_16x16x32_bf16(ah, bh, acc, 0, 0, 0);
    acc = __builtin_amdgcn_mfma_f32_16x16x32_bf16(al, bh, acc, 0, 0, 0);
    acc = __builtin_amdgcn_mfma_f32_16x16x32_bf16(ah, bl, acc, 0, 0, 0);
    return acc;
}

// ---------------- CSR build (padded to multiple of 4 per node) ----------------

__global__ void k_hist(const int* __restrict__ ei, int* __restrict__ cnt,
                       int* __restrict__ rank) {
    int e = blockIdx.x * blockDim.x + threadIdx.x;
    if (e < EE) rank[e] = atomicAdd(&cnt[ei[EE + e]], 1);
}

// exclusive scan over PADDED degrees
__global__ __launch_bounds__(1024) void k_scan1(const int* __restrict__ deg,
                                                int* __restrict__ excl,
                                                int* __restrict__ bsum) {
    __shared__ int ws[16];
    int tid = threadIdx.x, lane = tid & 63, w = tid >> 6;
    int gid = blockIdx.x * 1024 + tid;
    int v = (gid < NN) ? ((deg[gid] + 3) & ~3) : 0;
    int x = v;
    #pragma unroll
    for (int d = 1; d < 64; d <<= 1) {
        int y = __shfl_up(x, d);
        if (lane >= d) x += y;
    }
    if (lane == 63) ws[w] = x;
    __syncthreads();
    if (tid == 0) {
        int acc = 0;
        for (int i = 0; i < 16; i++) { int t = ws[i]; ws[i] = acc; acc += t; }
        bsum[blockIdx.x] = acc;
    }
    __syncthreads();
    if (gid < NN) excl[gid] = x - v + ws[w];
}

__global__ void k_scan2(const int* __restrict__ bsum, int* __restrict__ boff, int nb) {
    if (threadIdx.x == 0) {
        int acc = 0;
        for (int i = 0; i < nb; i++) { boff[i] = acc; acc += bsum[i]; }
        boff[nb] = acc;  // padded total
    }
}

__global__ __launch_bounds__(1024) void k_scan3(int* __restrict__ rp,
                                                const int* __restrict__ boff, int nb) {
    int gid = blockIdx.x * 1024 + threadIdx.x;
    if (gid < NN) rp[gid] += boff[blockIdx.x];
    if (gid == 0) rp[NN] = boff[nb];
}

// fill pad slots with sentinel node NN (P-row NN is all zeros)
__global__ void k_pad(const int* __restrict__ rp, const int* __restrict__ deg,
                      int* __restrict__ csrc) {
    int i = blockIdx.x * blockDim.x + threadIdx.x;
    if (i < NN) {
        int base = rp[i], d = deg[i], pd = rp[i + 1] - base;
        for (int j = d; j < pd; ++j) csrc[base + j] = NN;
    }
}

// zero the sentinel P-rows of both double-buffers
__global__ void k_zrow(unsigned short* __restrict__ PA,
                       unsigned short* __restrict__ PB) {
    int t = threadIdx.x;
    if (t < HD) PA[(size_t)NN * HD + t] = 0;
    else PB[(size_t)NN * HD + (t - HD)] = 0;
}

__global__ void k_scatter(const int* __restrict__ ei, const int* __restrict__ rp,
                          const int* __restrict__ rank, int* __restrict__ csrc) {
    int e = blockIdx.x * blockDim.x + threadIdx.x;
    if (e < EE) {
        int d = ei[EE + e];
        csrc[rp[d] + rank[e]] = ei[e];
    }
}

// ---------------- Encoder: h0 = x @ enc_W + enc_b, plus P0 = bf16(exp(msg)) ----------------

__global__ __launch_bounds__(256) void k_enc(const float* __restrict__ x,
                                             const float* __restrict__ W,
                                             const float* __restrict__ b,
                                             float* __restrict__ h,
                                             unsigned short* __restrict__ P0) {
    __shared__ float X[16 * 132];
    int tid = threadIdx.x, lane = tid & 63, w = tid >> 6;
    int nb = blockIdx.x * 16;
    int nq = lane >> 4, nr = lane & 15;
    int colbase = w * 16 + nr;

    {
        const float* src = x + (size_t)nb * IND + tid * 8;
        float4_ a = *(const float4_*)src;
        float4_ c = *(const float4_*)(src + 4);
        int m = tid >> 4, k8 = 8 * (tid & 15);
        *(float4_*)&X[m * 132 + k8] = a;
        *(float4_*)&X[m * 132 + k8 + 4] = c;
    }
    __syncthreads();

    float4_ acc = {};
    #pragma unroll
    for (int t = 0; t < 4; ++t) {
        short8 ah, al, bh, bl;
        split8(&X[nr * 132 + t * 32 + nq * 8], ah, al);
        load_b(W, HD, colbase, t * 32 + nq * 8, bh, bl);
        acc = mm3(ah, al, bh, bl, acc);
    }

    float bias = b[colbase];
    #pragma unroll
    for (int r = 0; r < 4; ++r) {
        int node = nb + nq * 4 + r;
        float y = acc[r] + bias;
        h[node * HD + colbase] = y;
        float msg = fminf(fmaxf(y, 0.f) + 1e-7f, 50.f);
        P0[node * HD + colbase] = f2b_rne(__expf(msg));
    }
}

// ---------------- GENConv layer: padded quarter-wave P-gather (no shfl, no mask)
//                  + MFMA matmul + residual + fused prenorm ----------------

__global__ __launch_bounds__(256) void k_layer(const unsigned short* __restrict__ Pin,
                                               const float* __restrict__ selfh,  // layer0 only
                                               const float* __restrict__ hres,
                                               float* __restrict__ hout,
                                               unsigned short* __restrict__ Pout,
                                               const int* __restrict__ rp,
                                               const int* __restrict__ csrc,
                                               const float* __restrict__ W,
                                               const float* __restrict__ b,
                                               const float* __restrict__ gnext,
                                               const float* __restrict__ bnext) {
    __shared__ float T[16 * 68];
    int tid = threadIdx.x, lane = tid & 63, w = tid >> 6;
    int nb = blockIdx.x * 16;
    int nq = lane >> 4, nr = lane & 15;
    int colbase = w * 16 + nr;

    // B fragments, register-resident
    short8 Bhi[2], Blo[2];
    #pragma unroll
    for (int t = 0; t < 2; ++t)
        load_b(W, HD, colbase, t * 32 + nq * 8, Bhi[t], Blo[t]);

    // quarter-wave gather: group g (lane>>4) owns edge k*4+g; lane covers
    // channels ci*4..ci*4+3 (dwordx2 of bf16 P). Padded CSR: every node's
    // segment is a multiple of 4 edges; pads point at zero-row NN.
    int g = lane >> 4;
    int ci = lane & 15;
    #pragma unroll 1
    for (int i = 0; i < 4; ++i) {
        int node = nb + w * 4 + i;
        int beg = rp[node];
        int nk = (rp[node + 1] - beg) >> 2;
        const int* ep = csrc + beg + g;
        float s0 = 0.f, s1 = 0.f, s2 = 0.f, s3 = 0.f;
        float n0 = 0.f, n1 = 0.f, n2 = 0.f, n3 = 0.f;
        #pragma unroll 2
        for (int k = 0; k < nk; ++k) {
            int src = ep[k * 4];   // 16-way broadcast, coalesced across groups
            const unsigned* pp = (const unsigned*)(Pin + ((size_t)src << 6)) + ci * 2;
            unsigned d0 = pp[0], d1 = pp[1];
            float p0 = __uint_as_float(d0 << 16);
            float p1 = __uint_as_float(d0 & 0xffff0000u);
            float p2 = __uint_as_float(d1 << 16);
            float p3 = __uint_as_float(d1 & 0xffff0000u);
            s0 += p0; s1 += p1; s2 += p2; s3 += p3;
            n0 = fmaf(p0, __log2f(fmaxf(p0, 1e-20f)), n0);
            n1 = fmaf(p1, __log2f(fmaxf(p1, 1e-20f)), n1);
            n2 = fmaf(p2, __log2f(fmaxf(p2, 1e-20f)), n2);
            n3 = fmaf(p3, __log2f(fmaxf(p3, 1e-20f)), n3);
        }
        // reduce across the 4 quarter-wave groups (lane bits 4,5)
        #pragma unroll
        for (int d = 16; d < 64; d <<= 1) {
            s0 += __shfl_xor(s0, d); s1 += __shfl_xor(s1, d);
            s2 += __shfl_xor(s2, d); s3 += __shfl_xor(s3, d);
            n0 += __shfl_xor(n0, d); n1 += __shfl_xor(n1, d);
            n2 += __shfl_xor(n2, d); n3 += __shfl_xor(n3, d);
        }
        if (g == 0) {
            float a0 = LN2 * n0 / fmaxf(s0, 1e-16f);
            float a1 = LN2 * n1 / fmaxf(s1, 1e-16f);
            float a2 = LN2 * n2 / fmaxf(s2, 1e-16f);
            float a3 = LN2 * n3 / fmaxf(s3, 1e-16f);
            float4_ xv;
            if (selfh) {
                float4_ sf = *(const float4_*)&selfh[(size_t)node * HD + ci * 4];
                xv[0] = sf[0] + a0; xv[1] = sf[1] + a1;
                xv[2] = sf[2] + a2; xv[3] = sf[3] + a3;
            } else {
                const unsigned* pp = (const unsigned*)(Pin + ((size_t)node << 6)) + ci * 2;
                unsigned d0 = pp[0], d1 = pp[1];
                xv[0] = LN2 * __log2f(__uint_as_float(d0 << 16)) - 1e-7f + a0;
                xv[1] = LN2 * __log2f(__uint_as_float(d0 & 0xffff0000u)) - 1e-7f + a1;
                xv[2] = LN2 * __log2f(__uint_as_float(d1 << 16)) - 1e-7f + a2;
                xv[3] = LN2 * __log2f(__uint_as_float(d1 & 0xffff0000u)) - 1e-7f + a3;
            }
            *(float4_*)&T[(w * 4 + i) * 68 + ci * 4] = xv;
        }
    }
    __syncthreads();

    short8 Ahi[2], Alo[2];
    #pragma unroll
    for (int t = 0; t < 2; ++t)
        split8(&T[nr * 68 + t * 32 + nq * 8], Ahi[t], Alo[t]);
    __syncthreads();  // all A reads done before T is overwritten

    float4_ acc = {};
    #pragma unroll
    for (int t = 0; t < 2; ++t)
        acc = mm3(Ahi[t], Alo[t], Bhi[t], Blo[t], acc);

    float bias = b[colbase];
    #pragma unroll
    for (int r = 0; r < 4; ++r) {
        int m = nq * 4 + r;
        int node = nb + m;
        float v = acc[r] + bias;
        if (hres) v += hres[node * HD + colbase];
        hout[node * HD + colbase] = v;
        T[m * 68 + colbase] = v;
    }
    if (!Pout) return;
    __syncthreads();

    // LN phase: thread -> node tid>>4, 4 channels; emit P = bf16(exp(msg))
    int m = tid >> 4, c4 = (tid & 15) * 4;
    float4_ vv = *(const float4_*)&T[m * 68 + c4];
    float ps_ = (vv[0] + vv[1]) + (vv[2] + vv[3]);
    float pq_ = (vv[0] * vv[0] + vv[1] * vv[1]) + (vv[2] * vv[2] + vv[3] * vv[3]);
    #pragma unroll
    for (int d = 8; d; d >>= 1) {
        ps_ += __shfl_xor(ps_, d);
        pq_ += __shfl_xor(pq_, d);
    }
    float mu = ps_ * (1.f / 64.f);
    float var = pq_ * (1.f / 64.f) - mu * mu;
    float inv = rsqrtf(fmaxf(var, 0.f) + 1e-5f);
    float4_ g4 = *(const float4_*)&gnext[c4];
    float4_ b4 = *(const float4_*)&bnext[c4];
    ushort4_ po;
    #pragma unroll
    for (int j = 0; j < 4; ++j) {
        float y = fmaxf((vv[j] - mu) * inv * g4[j] + b4[j], 0.f);
        float msg = fminf(y + 1e-7f, 50.f);
        po[j] = f2b_rne(__expf(msg));
    }
    *(ushort4_*)&Pout[(nb + m) * HD + c4] = po;
}

// ---------------- Predictor: out = h @ pred_W + pred_b  (MFMA) ----------------

__global__ __launch_bounds__(256) void k_pred(const float* __restrict__ h,
                                              const float* __restrict__ W,
                                              const float* __restrict__ b,
                                              float* __restrict__ out) {
    __shared__ float T[16 * 68];
    int tid = threadIdx.x, lane = tid & 63, w = tid >> 6;
    int nb = blockIdx.x * 16;
    int nq = lane >> 4, nr = lane & 15;

    {
        const float* src = h + (size_t)nb * HD + tid * 4;
        float4_ a = *(const float4_*)src;
        int m = tid >> 4, k4 = 4 * (tid & 15);
        *(float4_*)&T[m * 68 + k4] = a;
    }
    __syncthreads();

    short8 Ahi[2], Alo[2];
    #pragma unroll
    for (int t = 0; t < 2; ++t)
        split8(&T[nr * 68 + t * 32 + nq * 8], Ahi[t], Alo[t]);

    for (int tt = w; tt < 7; tt += 4) {
        int colbase = tt * 16 + nr;
        float4_ acc = {};
        #pragma unroll
        for (int t = 0; t < 2; ++t) {
            short8 bh, bl;
            load_b(W, OUTD, colbase, t * 32 + nq * 8, bh, bl);
            acc = mm3(Ahi[t], Alo[t], bh, bl, acc);
        }
        float bias = b[colbase];
        #pragma unroll
        for (int r = 0; r < 4; ++r) {
            int node = nb + nq * 4 + r;
            out[node * OUTD + colbase] = acc[r] + bias;
        }
    }
}

// ---------------- Launch ----------------

extern "C" void kernel_launch(void* const* d_in, const int* in_sizes, int n_in,
                              void* d_out, int out_size, void* d_ws, size_t ws_size,
                              hipStream_t stream) {
    const float* x    = (const float*)d_in[0];
    const int*   ei   = (const int*)d_in[1];
    const float* encW = (const float*)d_in[2];
    const float* encb = (const float*)d_in[3];
    const float* lng  = (const float*)d_in[4];
    const float* lnb  = (const float*)d_in[5];
    const float* mlpW = (const float*)d_in[6];
    const float* mlpb = (const float*)d_in[7];
    const float* pW   = (const float*)d_in[8];
    const float* pb   = (const float*)d_in[9];
    float* out = (float*)d_out;

    float* hA  = (float*)d_ws;
    float* hB  = hA + (size_t)NN * HD;
    unsigned short* PA = (unsigned short*)(hB + (size_t)NN * HD);       // (NN+1) rows
    unsigned short* PB = PA + (size_t)(NN + 1) * HD;                    // (NN+1) rows
    int* rp   = (int*)(PB + (size_t)(NN + 1) * HD);
    int* cnt  = rp + (NN + 1);
    int* csrc = cnt + NN;            // padded capacity: EE + 3*NN + 64
    int* rank = csrc + (EE + 3 * NN + 64);
    int* bsum = rank + EE;
    int* boff = bsum + 64;

    // CSR build (per call; ws is re-poisoned each launch)
    hipMemsetAsync(cnt, 0, NN * sizeof(int), stream);
    k_hist<<<(EE + 255) / 256, 256, 0, stream>>>(ei, cnt, rank);
    const int NB = (NN + 1023) / 1024;  // 49
    k_scan1<<<NB, 1024, 0, stream>>>(cnt, rp, bsum);
    k_scan2<<<1, 64, 0, stream>>>(bsum, boff, NB);
    k_scan3<<<NB, 1024, 0, stream>>>(rp, boff, NB);
    k_pad<<<(NN + 255) / 256, 256, 0, stream>>>(rp, cnt, csrc);
    k_zrow<<<1, 128, 0, stream>>>(PA, PB);
    k_scatter<<<(EE + 255) / 256, 256, 0, stream>>>(ei, rp, rank, csrc);

    // Encoder -> h_0 in hA, P_0 in PA
    k_enc<<<NN / 16, 256, 0, stream>>>(x, encW, encb, hA, PA);

    // Layer 0: self term = raw h0; writes h_1 -> hB, P_1 -> PB
    k_layer<<<NN / 16, 256, 0, stream>>>(PA, hA, nullptr, hB, PB, rp, csrc,
                                         mlpW, mlpb, lng, lnb);

    float* hres = hB;   // h_1
    float* hdst = hA;
    unsigned short* pc = PB;
    unsigned short* pn = PA;
    for (int l = 1; l < LL; ++l) {
        bool last = (l == LL - 1);
        k_layer<<<NN / 16, 256, 0, stream>>>(pc, nullptr, hres, hdst,
                                             last ? nullptr : pn,
                                             rp, csrc,
                                             mlpW + (size_t)l * HD * HD,
                                             mlpb + (size_t)l * HD,
                                             last ? nullptr : lng + (size_t)l * HD,
                                             last ? nullptr : lnb + (size_t)l * HD);
        float* t = hres; hres = hdst; hdst = t;
        unsigned short* u = pc; pc = pn; pn = u;
    }

    // Predictor on h_14
    k_pred<<<NN / 16, 256, 0, stream>>>(hres, pW, pb, out);
}